// Round 13
// baseline (264.226 us; speedup 1.0000x reference)
//
#include <hip/hip_runtime.h>
#include <math.h>

// ---------------------------------------------------------------------------
// QuantumTransformerE2E on MI355X — R13.
// Theory: tail scales with BLOCK COUNT (dispatch-rate floor ~240 blk/µs),
// not work. Changes vs R12 (225.6 µs):
//  (1) k_pre2: 2 chunks per 256-thr block (8192 blocks, was 16384).
//  (2) k_post4: 4 chunks per 512-thr block, fully parallel sub-blocks
//      (4096 blocks, was 16384). No serial chunk loops (R9 lesson).
// k_circ_cs / k_pool_cf / fallbacks verbatim R12.
// ---------------------------------------------------------------------------

constexpr int kNQ    = 6;
constexpr int kDM    = 128;
constexpr int kCH    = 4;
constexpr int kSEQ   = 2048;
constexpr int kCHUNK = 16;
constexpr int kBATCH = 128;
constexpr int kNCH   = kSEQ / kCHUNK;  // 128
constexpr int kNP    = 120;
constexpr float kPI  = 3.14159265358979323846f;

typedef __attribute__((ext_vector_type(8))) short bf16x8;
typedef __attribute__((ext_vector_type(4))) float f32x4;

__device__ __forceinline__ float fast_tanh(float x) {
  float e = __expf(-2.f * fabsf(x));
  float r = (1.f - e) * __builtin_amdgcn_rcpf(1.f + e);
  return copysignf(r, x);
}
__device__ __forceinline__ float fast_silu(float x) {
  return x * __builtin_amdgcn_rcpf(1.f + __expf(-x));
}

// quad_perm DPP helpers (VALU pipe).
template <int XM>
__device__ __forceinline__ float qp(float v) {
  constexpr int ctrl = (XM == 1) ? 0xB1 : 0x4E;
  return __int_as_float(
      __builtin_amdgcn_update_dpp(0, __float_as_int(v), ctrl, 0xF, 0xF, true));
}

// ---- register-resident 6-qubit gates (verified R8/R10) ---------------------

template <int RB>
__device__ __forceinline__ void rx_reg(float c, float s, float* sr, float* si) {
#pragma unroll
  for (int r0 = 0; r0 < 16; ++r0) {
    if (r0 & RB) continue;
    int r1 = r0 | RB;
    float ar = sr[r0], ai = si[r0], br = sr[r1], bi = si[r1];
    sr[r0] = fmaf(c, ar,  s * bi);  si[r0] = fmaf(c, ai, -s * br);
    sr[r1] = fmaf(c, br,  s * ai);  si[r1] = fmaf(c, bi, -s * ar);
  }
}

template <int RB>
__device__ __forceinline__ void ry_reg(float c, float s, float* sr, float* si) {
#pragma unroll
  for (int r0 = 0; r0 < 16; ++r0) {
    if (r0 & RB) continue;
    int r1 = r0 | RB;
    float ar = sr[r0], ai = si[r0], br = sr[r1], bi = si[r1];
    sr[r0] = fmaf(c, ar, -s * br);  si[r0] = fmaf(c, ai, -s * bi);
    sr[r1] = fmaf(s, ar,  c * br);  si[r1] = fmaf(s, ai,  c * bi);
  }
}

template <int RB>
__device__ __forceinline__ void rz_reg(float c, float s, float* sr, float* si) {
#pragma unroll
  for (int r = 0; r < 16; ++r) {
    float sp = (r & RB) ? s : -s;
    float ar = sr[r], ai = si[r];
    sr[r] = fmaf(c, ar, -sp * ai);
    si[r] = fmaf(c, ai,  sp * ar);
  }
}

template <int XM>
__device__ __forceinline__ void rx_lane(float c, float s, float* sr, float* si) {
#pragma unroll
  for (int r = 0; r < 16; ++r) {
    float pr = qp<XM>(sr[r]), pi = qp<XM>(si[r]);
    sr[r] = fmaf(c, sr[r],  s * pi);
    si[r] = fmaf(c, si[r], -s * pr);
  }
}

template <int XM>
__device__ __forceinline__ void ry_lane(float c, float sg, float* sr, float* si) {
#pragma unroll
  for (int r = 0; r < 16; ++r) {
    float pr = qp<XM>(sr[r]), pi = qp<XM>(si[r]);
    sr[r] = fmaf(c, sr[r], sg * pr);
    si[r] = fmaf(c, si[r], sg * pi);
  }
}

__device__ __forceinline__ void rz_lane(float c, float sp, float* sr, float* si) {
#pragma unroll
  for (int r = 0; r < 16; ++r) {
    float ar = sr[r], ai = si[r];
    sr[r] = fmaf(c, ar, -sp * ai);
    si[r] = fmaf(c, ai,  sp * ar);
  }
}

template <int RB, int CB>
__device__ __forceinline__ void crx_reg_reg(float c, float s, float* sr, float* si) {
#pragma unroll
  for (int r0 = 0; r0 < 16; ++r0) {
    if ((r0 & RB) || !(r0 & CB)) continue;
    int r1 = r0 | RB;
    float ar = sr[r0], ai = si[r0], br = sr[r1], bi = si[r1];
    sr[r0] = fmaf(c, ar,  s * bi);  si[r0] = fmaf(c, ai, -s * br);
    sr[r1] = fmaf(c, br,  s * ai);  si[r1] = fmaf(c, bi, -s * ar);
  }
}

template <int XM, int CB>
__device__ __forceinline__ void crx_reg_lane(float c, float s, float* sr, float* si) {
#pragma unroll
  for (int r = 0; r < 16; ++r) {
    if (!(r & CB)) continue;
    float pr = qp<XM>(sr[r]), pi = qp<XM>(si[r]);
    sr[r] = fmaf(c, sr[r],  s * pi);
    si[r] = fmaf(c, si[r], -s * pr);
  }
}

template <int RB>
__device__ __forceinline__ void meas_reg(const float* sr, const float* si,
                                         float& tr, float& ti, float& zz) {
  tr = 0.f; ti = 0.f; zz = 0.f;
#pragma unroll
  for (int r0 = 0; r0 < 16; ++r0) {
    float n = fmaf(sr[r0], sr[r0], si[r0] * si[r0]);
    zz += (r0 & RB) ? -n : n;
    if (r0 & RB) continue;
    int r1 = r0 | RB;
    tr = fmaf(sr[r0], sr[r1], fmaf(si[r0], si[r1], tr));
    ti = fmaf(sr[r0], si[r1], fmaf(-si[r0], sr[r1], ti));
  }
  tr += qp<1>(tr); tr += qp<2>(tr);
  ti += qp<1>(ti); ti += qp<2>(ti);
  zz += qp<1>(zz); zz += qp<2>(zz);
}

// ---------------------------------------------------------------------------
// k_pre2: 2 chunks per 256-thread block. Per-chunk logic identical to R10's
// verified k_pre; all LDS arrays indexed by cid = tid>>7.

__global__ __launch_bounds__(256) void k_pre2(
    const float* __restrict__ x,
    const float* __restrict__ conv_w, const float* __restrict__ conv_b,
    const float* __restrict__ ln1_g,  const float* __restrict__ ln1_b,
    const float* __restrict__ ca1_w,  const float* __restrict__ ca1_b,
    const float* __restrict__ ca2_w,  const float* __restrict__ ca2_b,
    const float* __restrict__ pp_w,   const float* __restrict__ pp_b,
    const float* __restrict__ ep_w,   const float* __restrict__ ep_b,
    float* __restrict__ outb, int emit_cs)
{
  __shared__ float hbuf[2][kCHUNK][132];
  __shared__ __align__(16) float spart[2][2][16];
  __shared__ __align__(16) float summ[2][kDM];
  __shared__ float mrow[2][kCHUNK], irow[2][kCHUNK];

  const int tid   = threadIdx.x;        // 0..255
  const int cid   = tid >> 7;           // sub-chunk 0/1
  const int t128  = tid & 127;
  const int chunk = blockIdx.x * 2 + cid;
  const int b     = chunk >> 7;
  const int nc    = chunk & 127;
  const int t0    = nc * kCHUNK;
  const int d     = t128;
  const int lane  = tid & 63;
  const int wv    = (tid >> 6) & 1;     // N-tile id within sub-chunk
  const int col   = (lane & 15) + 16 * wv;
  const int qd    = lane >> 4;

  // ---- early loads (fly under conv) ----
  float w12[12];
  {
    const float4* cw = (const float4*)(conv_w + d * 12);
    float4 a0 = cw[0], a1 = cw[1], a2 = cw[2];
    w12[0]=a0.x; w12[1]=a0.y; w12[2]=a0.z; w12[3]=a0.w;
    w12[4]=a1.x; w12[5]=a1.y; w12[6]=a1.z; w12[7]=a1.w;
    w12[8]=a2.x; w12[9]=a2.y; w12[10]=a2.z; w12[11]=a2.w;
  }
  float cb = conv_b[d];
  float g1 = ln1_g[d], b1 = ln1_b[d];
  float Bf[32];
#pragma unroll
  for (int ks = 0; ks < 4; ++ks)
#pragma unroll
    for (int jj = 0; jj < 8; ++jj)
      Bf[ks * 8 + jj] = ca1_w[(ks * 32 + qd * 8 + jj) * 32 + col];
  float cb1 = ca1_b[col], cw2 = ca2_w[col], cb2 = ca2_b[0];

  // ---- conv1d from global -> raw h regs + hbuf fp32 ----
  float h[kCHUNK];
#pragma unroll
  for (int t = 0; t < kCHUNK; ++t) h[t] = cb;
#pragma unroll
  for (int ch = 0; ch < kCH; ++ch) {
    const float* xb = x + ((size_t)b * kCH + ch) * kSEQ + t0 - 4;
    float xv[24];
#pragma unroll
    for (int sl = 1; sl <= 4; ++sl) {
      float4 v = *(const float4*)(xb + sl * 4);
      xv[sl*4+0]=v.x; xv[sl*4+1]=v.y; xv[sl*4+2]=v.z; xv[sl*4+3]=v.w;
    }
    if (nc > 0) {
      float4 v = *(const float4*)(xb);
      xv[0]=v.x; xv[1]=v.y; xv[2]=v.z; xv[3]=v.w;
    } else { xv[0]=xv[1]=xv[2]=xv[3]=0.f; }
    if (nc < 127) {
      float4 v = *(const float4*)(xb + 20);
      xv[20]=v.x; xv[21]=v.y; xv[22]=v.z; xv[23]=v.w;
    } else { xv[20]=xv[21]=xv[22]=xv[23]=0.f; }
    float c0 = w12[ch*3+0], c1 = w12[ch*3+1], c2 = w12[ch*3+2];
#pragma unroll
    for (int t = 0; t < kCHUNK; ++t)
      h[t] = fmaf(xv[t+3], c0, fmaf(xv[t+4], c1, fmaf(xv[t+5], c2, h[t])));
  }
#pragma unroll
  for (int t = 0; t < kCHUNK; ++t) hbuf[cid][t][d] = h[t];
  __syncthreads();

  // ---- LN1 stats: 8 lanes per row (lane-aligned groups), shfl combine ----
  {
    int row = t128 >> 3, k = t128 & 7;
    const float4* rp = (const float4*)&hbuf[cid][row][k * 16];
    float s1 = 0.f, s2 = 0.f;
#pragma unroll
    for (int q = 0; q < 4; ++q) {
      float4 v = rp[q];
      s1 += v.x + v.y + v.z + v.w;
      s2 = fmaf(v.x,v.x,s2); s2 = fmaf(v.y,v.y,s2);
      s2 = fmaf(v.z,v.z,s2); s2 = fmaf(v.w,v.w,s2);
    }
#pragma unroll
    for (int o = 1; o < 8; o <<= 1) {
      s1 += __shfl_xor(s1, o, 64);
      s2 += __shfl_xor(s2, o, 64);
    }
    if (k == 0) {
      float m = s1 * (1.f / kDM);
      mrow[cid][row] = m;
      irow[cid][row] = rsqrtf(s2 * (1.f / kDM) - m * m + 1e-5f);
    }
  }
  __syncthreads();

  // ---- LN1 apply in regs + write (hi,lo) bf16 pair per element ----
#pragma unroll
  for (int t = 0; t < kCHUNK; ++t) {
    h[t] = fmaf((h[t] - mrow[cid][t]) * irow[cid][t], g1, b1);
    unsigned hb = __float_as_uint(h[t]);
    float lof = h[t] - __uint_as_float(hb & 0xffff0000u);
    unsigned pk = (hb >> 16) | (__float_as_uint(lof) & 0xffff0000u);
    ((unsigned*)&hbuf[cid][t][0])[d] = pk;
  }
  __syncthreads();

  // ---- split B into bf16 hi/lo fragment vectors ----
  bf16x8 bhi[4], blo[4];
#pragma unroll
  for (int ks = 0; ks < 4; ++ks)
#pragma unroll
    for (int jj = 0; jj < 8; ++jj) {
      float bvf = Bf[ks * 8 + jj];
      unsigned bb = __float_as_uint(bvf);
      bhi[ks][jj] = (short)(bb >> 16);
      float lf = bvf - __uint_as_float(bb & 0xffff0000u);
      blo[ks][jj] = (short)(__float_as_uint(lf) >> 16);
    }

  // ---- MFMA GEMV: C[16][16] per wave, K=128 in 4 steps, 3-term split ----
  f32x4 acc = {0.f, 0.f, 0.f, 0.f};
  {
    const unsigned* hrow = (const unsigned*)&hbuf[cid][lane & 15][0];
#pragma unroll
    for (int ks = 0; ks < 4; ++ks) {
      const uint4* ap = (const uint4*)(hrow + ks * 32 + qd * 8);
      uint4 w0 = ap[0], w1 = ap[1];
      bf16x8 ahi, alo;
      ahi[0] = (short)(w0.x & 0xffff); ahi[1] = (short)(w0.y & 0xffff);
      ahi[2] = (short)(w0.z & 0xffff); ahi[3] = (short)(w0.w & 0xffff);
      ahi[4] = (short)(w1.x & 0xffff); ahi[5] = (short)(w1.y & 0xffff);
      ahi[6] = (short)(w1.z & 0xffff); ahi[7] = (short)(w1.w & 0xffff);
      alo[0] = (short)(w0.x >> 16); alo[1] = (short)(w0.y >> 16);
      alo[2] = (short)(w0.z >> 16); alo[3] = (short)(w0.w >> 16);
      alo[4] = (short)(w1.x >> 16); alo[5] = (short)(w1.y >> 16);
      alo[6] = (short)(w1.z >> 16); alo[7] = (short)(w1.w >> 16);
      acc = __builtin_amdgcn_mfma_f32_16x16x32_bf16(ahi, bhi[ks], acc, 0, 0, 0);
      acc = __builtin_amdgcn_mfma_f32_16x16x32_bf16(ahi, blo[ks], acc, 0, 0, 0);
      acc = __builtin_amdgcn_mfma_f32_16x16x32_bf16(alo, bhi[ks], acc, 0, 0, 0);
    }
  }

  // ---- tanh + ca2 weighting in C-layout, reduce over j (16 lanes) ----
  {
    float ev[4];
#pragma unroll
    for (int r = 0; r < 4; ++r)
      ev[r] = fast_tanh(acc[r] + cb1) * cw2;
#pragma unroll
    for (int o = 1; o < 16; o <<= 1)
#pragma unroll
      for (int r = 0; r < 4; ++r) ev[r] += __shfl_xor(ev[r], o, 64);
    if ((lane & 15) == 0)
      *(float4*)&spart[cid][wv][qd * 4] = make_float4(ev[0], ev[1], ev[2], ev[3]);
  }
  __syncthreads();

  // ---- all-thread redundant softmax + weighted sum from h regs ----
  {
    float scl16[kCHUNK];
    const float4* s0 = (const float4*)&spart[cid][0][0];
    const float4* s1 = (const float4*)&spart[cid][1][0];
    float mx = -1e30f;
#pragma unroll
    for (int g = 0; g < 4; ++g) {
      float4 a = s0[g], bq = s1[g];
      scl16[g*4+0] = a.x + bq.x + cb2;
      scl16[g*4+1] = a.y + bq.y + cb2;
      scl16[g*4+2] = a.z + bq.z + cb2;
      scl16[g*4+3] = a.w + bq.w + cb2;
    }
#pragma unroll
    for (int t = 0; t < kCHUNK; ++t) mx = fmaxf(mx, scl16[t]);
    float e[kCHUNK], ssum = 0.f;
#pragma unroll
    for (int t = 0; t < kCHUNK; ++t) { e[t] = __expf(scl16[t] - mx); ssum += e[t]; }
    float inv = 1.f / ssum;
    float acc2 = 0.f;
#pragma unroll
    for (int t = 0; t < kCHUNK; ++t) acc2 = fmaf(e[t] * inv, h[t], acc2);
    summ[cid][d] = acc2;
  }
  __syncthreads();

  // ---- projections -> (cos,sin) pairs (tier1) or half-angles (tier2) ----
  if (t128 < kNP) {
    float acc = pp_b[t128];
    const float4* s4 = (const float4*)&summ[cid][0];
#pragma unroll 8
    for (int q = 0; q < 32; ++q) {
      float4 v = s4[q];
      acc = fmaf(v.x, pp_w[(q*4+0)*kNP + t128], acc);
      acc = fmaf(v.y, pp_w[(q*4+1)*kNP + t128], acc);
      acc = fmaf(v.z, pp_w[(q*4+2)*kNP + t128], acc);
      acc = fmaf(v.w, pp_w[(q*4+3)*kNP + t128], acc);
    }
    float ha = 0.5f * acc;
    if (emit_cs) {
      ((float2*)(outb + (size_t)chunk * 256))[6 + t128] =
          make_float2(__cosf(ha), __sinf(ha));
    } else {
      outb[(size_t)chunk * 126 + 6 + t128] = ha;
    }
  } else if (t128 < kNP + kNQ) {
    int jj = t128 - kNP;
    float acc = ep_b[jj];
    const float4* s4 = (const float4*)&summ[cid][0];
#pragma unroll 8
    for (int q = 0; q < 32; ++q) {
      float4 v = s4[q];
      acc = fmaf(v.x, ep_w[(q*4+0)*kNQ + jj], acc);
      acc = fmaf(v.y, ep_w[(q*4+1)*kNQ + jj], acc);
      acc = fmaf(v.z, ep_w[(q*4+2)*kNQ + jj], acc);
      acc = fmaf(v.w, ep_w[(q*4+3)*kNQ + jj], acc);
    }
    float ha = 0.5f * fast_tanh(acc) * kPI;
    if (emit_cs) {
      ((float2*)(outb + (size_t)chunk * 256))[jj] =
          make_float2(__cosf(ha), __sinf(ha));
    } else {
      outb[(size_t)chunk * 126 + jj] = ha;
    }
  }
}

// ---------------------------------------------------------------------------
// k_circ_cs: verbatim R12 (LDS-staged cs pairs, zero transcendentals).

constexpr int kCsStride = 260;

__global__ __launch_bounds__(64) void k_circ_cs(const float* __restrict__ csA,
                                                float* __restrict__ qv_g)
{
  __shared__ __align__(16) float lds[16 * kCsStride];

  const int lane  = threadIdx.x;
  const int c     = lane >> 2;
  const int l     = lane & 3;
  const int chunk = blockIdx.x * 16 + c;
  const int b0 = (l >> 1) & 1;
  const int b1 = l & 1;

  {
    const float4* src = (const float4*)(csA + (size_t)blockIdx.x * 16 * 256);
#pragma unroll
    for (int i = 0; i < 16; ++i) {
      float4 v = src[i * 64 + lane];
      *(float4*)&lds[i * kCsStride + lane * 4] = v;
    }
  }
  __syncthreads();

  const float2* cp = (const float2*)&lds[c * kCsStride];

  float sr[16], si[16];
#pragma unroll
  for (int r = 0; r < 16; ++r) { sr[r] = 0.f; si[r] = 0.f; }
  sr[0] = (l == 0) ? 1.f : 0.f;

  {
    float2 q0 = cp[0], q1 = cp[1], q2 = cp[2], q3 = cp[3], q4 = cp[4], q5 = cp[5];
    ry_lane<2>(q0.x, b0 ? q0.y : -q0.y, sr, si);
    ry_lane<1>(q1.x, b1 ? q1.y : -q1.y, sr, si);
    ry_reg<8>(q2.x, q2.y, sr, si);
    ry_reg<4>(q3.x, q3.y, sr, si);
    ry_reg<2>(q4.x, q4.y, sr, si);
    ry_reg<1>(q5.x, q5.y, sr, si);
  }

  for (int a = 0; a < 4; ++a) {
    const float2* pb = cp + 6 + a * 30;
    float2 t;
    t = pb[0];  rx_lane<2>(t.x, t.y, sr, si);
    t = pb[1];  ry_lane<2>(t.x, b0 ? t.y : -t.y, sr, si);
    t = pb[2];  rz_lane   (t.x, b0 ? t.y : -t.y, sr, si);
    t = pb[3];  rx_lane<1>(t.x, t.y, sr, si);
    t = pb[4];  ry_lane<1>(t.x, b1 ? t.y : -t.y, sr, si);
    t = pb[5];  rz_lane   (t.x, b1 ? t.y : -t.y, sr, si);
    t = pb[6];  rx_reg<8>(t.x, t.y, sr, si);
    t = pb[7];  ry_reg<8>(t.x, t.y, sr, si);
    t = pb[8];  rz_reg<8>(t.x, t.y, sr, si);
    t = pb[9];  rx_reg<4>(t.x, t.y, sr, si);
    t = pb[10]; ry_reg<4>(t.x, t.y, sr, si);
    t = pb[11]; rz_reg<4>(t.x, t.y, sr, si);
    t = pb[12]; rx_reg<2>(t.x, t.y, sr, si);
    t = pb[13]; ry_reg<2>(t.x, t.y, sr, si);
    t = pb[14]; rz_reg<2>(t.x, t.y, sr, si);
    t = pb[15]; rx_reg<1>(t.x, t.y, sr, si);
    t = pb[16]; ry_reg<1>(t.x, t.y, sr, si);
    t = pb[17]; rz_reg<1>(t.x, t.y, sr, si);
    t = pb[18]; { float c2 = b0 ? t.x : 1.f, s2 = b0 ? t.y : 0.f; rx_lane<1>(c2, s2, sr, si); }
    t = pb[19]; { float c2 = b1 ? t.x : 1.f, s2 = b1 ? t.y : 0.f; rx_reg<8>(c2, s2, sr, si); }
    t = pb[20]; crx_reg_reg<4, 8>(t.x, t.y, sr, si);
    t = pb[21]; crx_reg_reg<2, 4>(t.x, t.y, sr, si);
    t = pb[22]; crx_reg_reg<1, 2>(t.x, t.y, sr, si);
    t = pb[23]; crx_reg_lane<2, 1>(t.x, t.y, sr, si);
    t = pb[24]; crx_reg_reg<2, 1>(t.x, t.y, sr, si);
    t = pb[25]; crx_reg_reg<4, 2>(t.x, t.y, sr, si);
    t = pb[26]; crx_reg_reg<8, 4>(t.x, t.y, sr, si);
    t = pb[27]; crx_reg_lane<1, 8>(t.x, t.y, sr, si);
    t = pb[28]; { float c2 = b1 ? t.x : 1.f, s2 = b1 ? t.y : 0.f; rx_lane<2>(c2, s2, sr, si); }
    t = pb[29]; { float c2 = b0 ? t.x : 1.f, s2 = b0 ? t.y : 0.f; rx_reg<1>(c2, s2, sr, si); }
  }

  float res[18];
  {
    float tr = 0.f, ti = 0.f, zz = 0.f;
#pragma unroll
    for (int r = 0; r < 16; ++r) {
      float pr = qp<2>(sr[r]), pi = qp<2>(si[r]);
      tr = fmaf(sr[r], pr, fmaf(si[r], pi, tr));
      ti = fmaf(sr[r], pi, fmaf(-si[r], pr, ti));
      zz = fmaf(sr[r], sr[r], fmaf(si[r], si[r], zz));
    }
    tr = b0 ? 0.f : tr;  ti = b0 ? 0.f : ti;  zz = b0 ? -zz : zz;
    tr += qp<1>(tr); tr += qp<2>(tr);
    ti += qp<1>(ti); ti += qp<2>(ti);
    zz += qp<1>(zz); zz += qp<2>(zz);
    res[0] = 2.f * tr; res[6] = 2.f * ti; res[12] = zz;
  }
  {
    float tr = 0.f, ti = 0.f, zz = 0.f;
#pragma unroll
    for (int r = 0; r < 16; ++r) {
      float pr = qp<1>(sr[r]), pi = qp<1>(si[r]);
      tr = fmaf(sr[r], pr, fmaf(si[r], pi, tr));
      ti = fmaf(sr[r], pi, fmaf(-si[r], pr, ti));
      zz = fmaf(sr[r], sr[r], fmaf(si[r], si[r], zz));
    }
    tr = b1 ? 0.f : tr;  ti = b1 ? 0.f : ti;  zz = b1 ? -zz : zz;
    tr += qp<1>(tr); tr += qp<2>(tr);
    ti += qp<1>(ti); ti += qp<2>(ti);
    zz += qp<1>(zz); zz += qp<2>(zz);
    res[1] = 2.f * tr; res[7] = 2.f * ti; res[13] = zz;
  }
  {
    float tr, ti, zz;
    meas_reg<8>(sr, si, tr, ti, zz); res[2] = 2.f*tr; res[8]  = 2.f*ti; res[14] = zz;
    meas_reg<4>(sr, si, tr, ti, zz); res[3] = 2.f*tr; res[9]  = 2.f*ti; res[15] = zz;
    meas_reg<2>(sr, si, tr, ti, zz); res[4] = 2.f*tr; res[10] = 2.f*ti; res[16] = zz;
    meas_reg<1>(sr, si, tr, ti, zz); res[5] = 2.f*tr; res[11] = 2.f*ti; res[17] = zz;
  }
  if (l == 0) {
    float* qo = qv_g + (size_t)chunk * 18;
#pragma unroll
    for (int k = 0; k < 18; ++k) qo[k] = res[k];
  }
}

// ---------------------------------------------------------------------------
// k_circ: tier2 (verbatim R10) — reads half-angles stride 126, computes sincos.

__global__ __launch_bounds__(64) void k_circ(const float* __restrict__ csb_g,
                                             float* __restrict__ qv_g)
{
  const int lane  = threadIdx.x;
  const int c     = lane >> 2;
  const int l     = lane & 3;
  const int chunk = blockIdx.x * 16 + c;
  const float* cp = csb_g + (size_t)chunk * 126;
  const int b0 = (l >> 1) & 1;
  const int b1 = l & 1;

  float sr[16], si[16];
#pragma unroll
  for (int r = 0; r < 16; ++r) { sr[r] = 0.f; si[r] = 0.f; }
  sr[0] = (l == 0) ? 1.f : 0.f;

  {
    float gc[6], gs[6];
#pragma unroll
    for (int g = 0; g < 6; ++g) { float th = cp[g]; gc[g] = __cosf(th); gs[g] = __sinf(th); }
    ry_lane<2>(gc[0], b0 ? gs[0] : -gs[0], sr, si);
    ry_lane<1>(gc[1], b1 ? gs[1] : -gs[1], sr, si);
    ry_reg<8>(gc[2], gs[2], sr, si);
    ry_reg<4>(gc[3], gs[3], sr, si);
    ry_reg<2>(gc[4], gs[4], sr, si);
    ry_reg<1>(gc[5], gs[5], sr, si);
  }

  for (int a = 0; a < 4; ++a) {
    const float* pb = cp + 6 + a * 30;
    float gc[30], gs[30];
#pragma unroll
    for (int g = 0; g < 30; ++g) { float th = pb[g]; gc[g] = __cosf(th); gs[g] = __sinf(th); }
    rx_lane<2>(gc[0], gs[0], sr, si);
    ry_lane<2>(gc[1], b0 ? gs[1] : -gs[1], sr, si);
    rz_lane   (gc[2], b0 ? gs[2] : -gs[2], sr, si);
    rx_lane<1>(gc[3], gs[3], sr, si);
    ry_lane<1>(gc[4], b1 ? gs[4] : -gs[4], sr, si);
    rz_lane   (gc[5], b1 ? gs[5] : -gs[5], sr, si);
    rx_reg<8>(gc[6],  gs[6],  sr, si);  ry_reg<8>(gc[7],  gs[7],  sr, si);  rz_reg<8>(gc[8],  gs[8],  sr, si);
    rx_reg<4>(gc[9],  gs[9],  sr, si);  ry_reg<4>(gc[10], gs[10], sr, si);  rz_reg<4>(gc[11], gs[11], sr, si);
    rx_reg<2>(gc[12], gs[12], sr, si);  ry_reg<2>(gc[13], gs[13], sr, si);  rz_reg<2>(gc[14], gs[14], sr, si);
    rx_reg<1>(gc[15], gs[15], sr, si);  ry_reg<1>(gc[16], gs[16], sr, si);  rz_reg<1>(gc[17], gs[17], sr, si);
    { float c2 = b0 ? gc[18] : 1.f, s2 = b0 ? gs[18] : 0.f; rx_lane<1>(c2, s2, sr, si); }
    { float c2 = b1 ? gc[19] : 1.f, s2 = b1 ? gs[19] : 0.f; rx_reg<8>(c2, s2, sr, si); }
    crx_reg_reg<4, 8>(gc[20], gs[20], sr, si);
    crx_reg_reg<2, 4>(gc[21], gs[21], sr, si);
    crx_reg_reg<1, 2>(gc[22], gs[22], sr, si);
    crx_reg_lane<2, 1>(gc[23], gs[23], sr, si);
    crx_reg_reg<2, 1>(gc[24], gs[24], sr, si);
    crx_reg_reg<4, 2>(gc[25], gs[25], sr, si);
    crx_reg_reg<8, 4>(gc[26], gs[26], sr, si);
    crx_reg_lane<1, 8>(gc[27], gs[27], sr, si);
    { float c2 = b1 ? gc[28] : 1.f, s2 = b1 ? gs[28] : 0.f; rx_lane<2>(c2, s2, sr, si); }
    { float c2 = b0 ? gc[29] : 1.f, s2 = b0 ? gs[29] : 0.f; rx_reg<1>(c2, s2, sr, si); }
  }

  float res[18];
  {
    float tr = 0.f, ti = 0.f, zz = 0.f;
#pragma unroll
    for (int r = 0; r < 16; ++r) {
      float pr = qp<2>(sr[r]), pi = qp<2>(si[r]);
      tr = fmaf(sr[r], pr, fmaf(si[r], pi, tr));
      ti = fmaf(sr[r], pi, fmaf(-si[r], pr, ti));
      zz = fmaf(sr[r], sr[r], fmaf(si[r], si[r], zz));
    }
    tr = b0 ? 0.f : tr;  ti = b0 ? 0.f : ti;  zz = b0 ? -zz : zz;
    tr += qp<1>(tr); tr += qp<2>(tr);
    ti += qp<1>(ti); ti += qp<2>(ti);
    zz += qp<1>(zz); zz += qp<2>(zz);
    res[0] = 2.f * tr; res[6] = 2.f * ti; res[12] = zz;
  }
  {
    float tr = 0.f, ti = 0.f, zz = 0.f;
#pragma unroll
    for (int r = 0; r < 16; ++r) {
      float pr = qp<1>(sr[r]), pi = qp<1>(si[r]);
      tr = fmaf(sr[r], pr, fmaf(si[r], pi, tr));
      ti = fmaf(sr[r], pi, fmaf(-si[r], pr, ti));
      zz = fmaf(sr[r], sr[r], fmaf(si[r], si[r], zz));
    }
    tr = b1 ? 0.f : tr;  ti = b1 ? 0.f : ti;  zz = b1 ? -zz : zz;
    tr += qp<1>(tr); tr += qp<2>(tr);
    ti += qp<1>(ti); ti += qp<2>(ti);
    zz += qp<1>(zz); zz += qp<2>(zz);
    res[1] = 2.f * tr; res[7] = 2.f * ti; res[13] = zz;
  }
  {
    float tr, ti, zz;
    meas_reg<8>(sr, si, tr, ti, zz); res[2] = 2.f*tr; res[8]  = 2.f*ti; res[14] = zz;
    meas_reg<4>(sr, si, tr, ti, zz); res[3] = 2.f*tr; res[9]  = 2.f*ti; res[15] = zz;
    meas_reg<2>(sr, si, tr, ti, zz); res[4] = 2.f*tr; res[10] = 2.f*ti; res[16] = zz;
    meas_reg<1>(sr, si, tr, ti, zz); res[5] = 2.f*tr; res[11] = 2.f*ti; res[17] = zz;
  }
  if (l == 0) {
    float* qo = qv_g + (size_t)chunk * 18;
#pragma unroll
    for (int k = 0; k < 18; ++k) qo[k] = res[k];
  }
}

// ---------------------------------------------------------------------------
// k_post4: 4 chunks per 512-thread block, fully parallel sub-blocks.

__global__ __launch_bounds__(512) void k_post4(
    const float* __restrict__ qv_g,
    const float* __restrict__ op_w, const float* __restrict__ op_b,
    const float* __restrict__ ln2_g, const float* __restrict__ ln2_b,
    const float* __restrict__ sa1_w, const float* __restrict__ sa1_b,
    const float* __restrict__ sa2_w, const float* __restrict__ sa2_b,
    float* __restrict__ cf, float* __restrict__ sclb)
{
  __shared__ float cfs[4][132];
  __shared__ float part1[4][32];
  __shared__ float red[4][4];

  const int tid  = threadIdx.x;
  const int sc   = tid >> 7;          // sub-chunk 0..3
  const int t128 = tid & 127, d = t128;
  const int j = t128 & 31, sub = t128 >> 5;
  const int chunk = blockIdx.x * 4 + sc;

  float qv[18];
  {
    const float* qpp = qv_g + (size_t)chunk * 18;
#pragma unroll
    for (int k = 0; k < 18; ++k) qv[k] = qpp[k];
  }
  float acc = op_b[d];
#pragma unroll
  for (int k = 0; k < 18; ++k) acc = fmaf(qv[k], op_w[k * kDM + d], acc);

  float v = acc, v2 = acc * acc;
#pragma unroll
  for (int o = 32; o; o >>= 1) { v += __shfl_xor(v, o, 64); v2 += __shfl_xor(v2, o, 64); }
  if ((t128 & 63) == 0) { red[sc][t128 >> 6] = v; red[sc][2 + (t128 >> 6)] = v2; }
  __syncthreads();
  float s1 = red[sc][0] + red[sc][1], s2 = red[sc][2] + red[sc][3];
  float m = s1 * (1.f / kDM);
  float var = s2 * (1.f / kDM) - m * m;
  float xn = fmaf((acc - m) * rsqrtf(var + 1e-5f), ln2_g[d], ln2_b[d]);
  float cfv = fast_silu(xn);
  cf[(size_t)chunk * kDM + d] = cfv;
  cfs[sc][d] = cfv;
  __syncthreads();

  float acc2 = 0.f;
  {
    const float* wp2 = sa1_w + (sub * 32) * 32 + j;
#pragma unroll
    for (int q = 0; q < 8; ++q) {
      float4 hv = *(const float4*)&cfs[sc][sub * 32 + q * 4];
      acc2 = fmaf(hv.x, wp2[(q*4+0)*32], acc2);
      acc2 = fmaf(hv.y, wp2[(q*4+1)*32], acc2);
      acc2 = fmaf(hv.z, wp2[(q*4+2)*32], acc2);
      acc2 = fmaf(hv.w, wp2[(q*4+3)*32], acc2);
    }
  }
  acc2 += __shfl_xor(acc2, 32, 64);
  if (sub == 2) part1[sc][j] = acc2;
  __syncthreads();
  if (t128 < 32) {
    float hv = fast_tanh(acc2 + part1[sc][j] + sa1_b[j]) * sa2_w[j];
#pragma unroll
    for (int o = 16; o; o >>= 1) hv += __shfl_xor(hv, o, 64);
    if (j == 0) sclb[chunk] = hv + sa2_b[0];
  }
}

// ---------------------------------------------------------------------------
// k_pool_cf: verbatim R12 (verified R6).

__global__ __launch_bounds__(512) void k_pool_cf(
    const float* __restrict__ cf, const float* __restrict__ scl,
    const float* __restrict__ cl1_w, const float* __restrict__ cl1_b,
    const float* __restrict__ cl2_w, const float* __restrict__ cl2_b,
    float* __restrict__ out)
{
  __shared__ float wl[kNCH];
  __shared__ float rep4[4][kDM];
  __shared__ float ulp[8][64];
  __shared__ float ul[64];
  __shared__ float red2[16];
  int b = blockIdx.x, tid = threadIdx.x;
  int idx = tid & 127, wid = tid >> 6;
  float s = scl[b*kNCH + idx];
  float mx = s;
#pragma unroll
  for (int o = 32; o; o >>= 1) mx = fmaxf(mx, __shfl_xor(mx,o,64));
  if ((tid & 63) == 0) red2[wid] = mx;
  __syncthreads();
  mx = fmaxf(red2[0], red2[1]);
  float e = __expf(s - mx);
  float se = e;
#pragma unroll
  for (int o = 32; o; o >>= 1) se += __shfl_xor(se,o,64);
  if ((tid & 63) == 0) red2[8+wid] = se;
  if (tid < kNCH) wl[tid] = e;
  __syncthreads();
  float inv = 1.f/(red2[8]+red2[9]);
  {
    int dd = tid & 127, qq = tid >> 7;
    const float* cfb = cf + (size_t)b*kNCH*kDM + (size_t)qq*32*kDM;
    const float* wlq = wl + qq*32;
    float a0=0,a1=0,a2=0,a3=0;
#pragma unroll 4
    for (int ncc = 0; ncc < 32; ncc += 4) {
      a0 = fmaf(wlq[ncc+0], cfb[(ncc+0)*kDM+dd], a0);
      a1 = fmaf(wlq[ncc+1], cfb[(ncc+1)*kDM+dd], a1);
      a2 = fmaf(wlq[ncc+2], cfb[(ncc+2)*kDM+dd], a2);
      a3 = fmaf(wlq[ncc+3], cfb[(ncc+3)*kDM+dd], a3);
    }
    rep4[qq][dd] = (a0+a1)+(a2+a3);
  }
  __syncthreads();
  {
    int jj = tid & 63, qq = tid >> 6;
    float accp = 0.f;
#pragma unroll
    for (int k = 0; k < 16; ++k) {
      int dd = qq*16 + k;
      float rv = ((rep4[0][dd]+rep4[1][dd])+(rep4[2][dd]+rep4[3][dd]))*inv;
      accp = fmaf(rv, cl1_w[dd*64+jj], accp);
    }
    ulp[qq][jj] = accp;
  }
  __syncthreads();
  if (tid < 64) {
    float acc = cl1_b[tid];
#pragma unroll
    for (int q = 0; q < 8; ++q) acc += ulp[q][tid];
    ul[tid] = fast_silu(acc);
  }
  __syncthreads();
  if (tid < 2) {
    float acc = cl2_b[tid];
#pragma unroll
    for (int k = 0; k < 64; ++k) acc = fmaf(ul[k], cl2_w[k*2+tid], acc);
    out[b*2+tid] = acc;
  }
}

// ---------------------------------------------------------------------------

extern "C" void kernel_launch(void* const* d_in, const int* in_sizes, int n_in,
                              void* d_out, int out_size, void* d_ws, size_t ws_size,
                              hipStream_t stream) {
  const float* x      = (const float*)d_in[0];
  const float* conv_w = (const float*)d_in[1];
  const float* conv_b = (const float*)d_in[2];
  const float* ln1_g  = (const float*)d_in[3];
  const float* ln1_b  = (const float*)d_in[4];
  const float* ca1_w  = (const float*)d_in[5];
  const float* ca1_b  = (const float*)d_in[6];
  const float* ca2_w  = (const float*)d_in[7];
  const float* ca2_b  = (const float*)d_in[8];
  const float* pp_w   = (const float*)d_in[9];
  const float* pp_b   = (const float*)d_in[10];
  const float* ep_w   = (const float*)d_in[11];
  const float* ep_b   = (const float*)d_in[12];
  const float* op_w   = (const float*)d_in[13];
  const float* op_b   = (const float*)d_in[14];
  const float* ln2_g  = (const float*)d_in[15];
  const float* ln2_b  = (const float*)d_in[16];
  const float* sa1_w  = (const float*)d_in[17];
  const float* sa1_b  = (const float*)d_in[18];
  const float* sa2_w  = (const float*)d_in[19];
  const float* sa2_b  = (const float*)d_in[20];
  const float* cl1_w  = (const float*)d_in[21];
  const float* cl1_b  = (const float*)d_in[22];
  const float* cl2_w  = (const float*)d_in[23];
  const float* cl2_b  = (const float*)d_in[24];
  float* out = (float*)d_out;

  const size_t nch   = (size_t)kBATCH * kNCH;  // 16384
  const size_t fCS   = nch * 256;
  const size_t need1 = (fCS + nch * 18 + nch) * sizeof(float);   // 18.0 MB
  const size_t fA    = nch * kDM;
  const size_t need2 = (fA + nch * 18 + nch) * sizeof(float);    // 9.5 MB

  if (ws_size >= need1) {
    float* csA   = (float*)d_ws;
    float* cf    = csA;              // aliased: csA dead after k_circ_cs
    float* qv_g  = csA + fCS;
    float* sclb  = qv_g + nch * 18;
    k_pre2<<<(kBATCH * kNCH) / 2, 256, 0, stream>>>(
        x, conv_w, conv_b, ln1_g, ln1_b, ca1_w, ca1_b, ca2_w, ca2_b,
        pp_w, pp_b, ep_w, ep_b, csA, 1);
    k_circ_cs<<<(kBATCH * kNCH) / 16, 64, 0, stream>>>(csA, qv_g);
    k_post4<<<(kBATCH * kNCH) / 4, 512, 0, stream>>>(
        qv_g, op_w, op_b, ln2_g, ln2_b, sa1_w, sa1_b, sa2_w, sa2_b, cf, sclb);
    k_pool_cf<<<kBATCH, 512, 0, stream>>>(
        cf, sclb, cl1_w, cl1_b, cl2_w, cl2_b, out);
  } else {
    // tier2: half-angle path (k_circ computes sincos); same grids.
    float* A     = (float*)d_ws;
    float* qv_g  = A + fA;
    float* sclb  = qv_g + nch * 18;
    k_pre2<<<(kBATCH * kNCH) / 2, 256, 0, stream>>>(
        x, conv_w, conv_b, ln1_g, ln1_b, ca1_w, ca1_b, ca2_w, ca2_b,
        pp_w, pp_b, ep_w, ep_b, A, 0);
    k_circ<<<(kBATCH * kNCH) / 16, 64, 0, stream>>>(A, qv_g);
    k_post4<<<(kBATCH * kNCH) / 4, 512, 0, stream>>>(
        qv_g, op_w, op_b, ln2_g, ln2_b, sa1_w, sa1_b, sa2_w, sa2_b, A, sclb);
    k_pool_cf<<<kBATCH, 512, 0, stream>>>(
        A, sclb, cl1_w, cl1_b, cl2_w, cl2_b, out);
  }
}